// Round 10
// baseline (397.404 us; speedup 1.0000x reference)
//
#include <hip/hip_runtime.h>
#include <hip/hip_bf16.h>

typedef unsigned short u16;
typedef unsigned int u32;

typedef short bf16v8 __attribute__((ext_vector_type(8)));
typedef float f32v4 __attribute__((ext_vector_type(4)));

// ---------------- problem constants ----------------
constexpr int BB   = 64;
constexpr int TT   = 196;
constexpr int NTOK = BB * TT;   // 12544
constexpr int DD   = 512;
constexpr int FF   = 2048;
constexpr int EE   = 8;
constexpr int NBR  = 2;
constexpr int GE   = NBR * EE;  // 16 global experts
constexpr int MT256 = 114;      // >= max total 256-row tiles (<=112)

// meta: [0..15] u-row base (cumsum); [34] n256; [320..320+n256) (ge<<20)|tile
__device__ __forceinline__ u16 f2bf(float f) {
    union { float f; u32 u; } v; v.f = f;
    u32 r = v.u + 0x7fffu + ((v.u >> 16) & 1u);
    return (u16)(r >> 16);
}

__device__ __forceinline__ float bf2f(u32 u) {
    union { u32 u; float f; } v; v.u = u << 16; return v.f;
}

__device__ __forceinline__ float wave_sum(float v) {
    #pragma unroll
    for (int m = 32; m > 0; m >>= 1) v += __shfl_xor(v, m, 64);
    return v;
}

// tanh-approx gelu via sigmoid: gelu(v) = v * sigmoid(1.596v + 0.0714v^3)
__device__ __forceinline__ float gelu_tanh(float v) {
    float y = 1.595769122f * v + 0.071354816f * (v * v * v);
    return v / (1.0f + __expf(-y));
}

__device__ __forceinline__ float silu(float v) {
    return v / (1.0f + __expf(-v));
}

__device__ __forceinline__ void gload16(const u16* g, u16* l) {
    typedef const __attribute__((address_space(1))) unsigned gv_t;
    typedef __attribute__((address_space(3))) unsigned lv_t;
    __builtin_amdgcn_global_load_lds((gv_t*)g, (lv_t*)l, 16, 0, 0);
}

__device__ __forceinline__ void bar() {
    asm volatile("" ::: "memory");
    __builtin_amdgcn_s_barrier();
    asm volatile("" ::: "memory");
}

#define ASM_VMCNT4 asm volatile("s_waitcnt vmcnt(4)" ::: "memory")
#define ASM_VMCNT0 asm volatile("s_waitcnt vmcnt(0)" ::: "memory")
#define ASM_LGKM0  asm volatile("s_waitcnt lgkmcnt(0)" ::: "memory")

// ---------------- merged: weight transposes + eo GEMM + cnt init ------------
// grid: [0,4096) w1 64x64 tiles; [4096,8192) w2; [8192,8256) out_w; [8256,8320) eo
__global__ __launch_bounds__(256) void mtrans_eo_kernel(
    const float* __restrict__ w1, u16* __restrict__ w1t,
    const float* __restrict__ w2, u16* __restrict__ w2t,
    const float* __restrict__ ow, u16* __restrict__ owt,
    const float* __restrict__ emb, const float* __restrict__ emb_w,
    const float* __restrict__ emb_b, float* __restrict__ eo,
    int* __restrict__ cnt)
{
    __shared__ float tile[64][69];
    __shared__ float se[4][DD];
    int id = blockIdx.x;
    int t = threadIdx.x;

    if (id >= 8256) {              // ---- eo: silu(emb) @ emb_w + emb_b ----
        int id2 = id - 8256;
        int cg = id2 & 3, bg = id2 >> 2;
        int b0 = bg * 4;
        int c0 = cg * 256 + t;
        for (int i = t; i < 4 * DD; i += 256) {
            int b = i >> 9, d = i & (DD - 1);
            se[b][d] = silu(emb[(size_t)(b0 + b) * DD + d]);
        }
        __syncthreads();
        float acc[4] = {0, 0, 0, 0};
        for (int k = 0; k < DD; ++k) {
            float wv = emb_w[(size_t)k * 1024 + c0];
            #pragma unroll
            for (int b = 0; b < 4; ++b) acc[b] += se[b][k] * wv;
        }
        float bb = emb_b[c0];
        #pragma unroll
        for (int b = 0; b < 4; ++b)
            eo[(size_t)(b0 + b) * 1024 + c0] = acc[b] + bb;
        return;
    }

    if (id == 0 && t < 16) cnt[t] = 0;

    const float* src; u16* dst; int R, C, rt, ct;
    if (id < 4096) {
        int e = id >> 8, rem = id & 255;
        R = DD; C = FF; rt = rem >> 5; ct = rem & 31;
        src = w1 + (size_t)e * R * C; dst = w1t + (size_t)e * R * C;
    } else if (id < 8192) {
        int e = (id - 4096) >> 8, rem = (id - 4096) & 255;
        R = FF; C = DD; rt = rem >> 3; ct = rem & 7;
        src = w2 + (size_t)e * R * C; dst = w2t + (size_t)e * R * C;
    } else {
        int rem = id - 8192;
        R = DD; C = DD; rt = rem >> 3; ct = rem & 7;
        src = ow; dst = owt;
    }
    int tx = t & 15, ty = t >> 4;
    int r0 = rt * 64, c0 = ct * 64;
    #pragma unroll
    for (int j = 0; j < 4; ++j) {
        int row = ty + j * 16;
        float4 v = *(const float4*)&src[(size_t)(r0 + row) * C + c0 + tx * 4];
        tile[row][tx * 4 + 0] = v.x;
        tile[row][tx * 4 + 1] = v.y;
        tile[row][tx * 4 + 2] = v.z;
        tile[row][tx * 4 + 3] = v.w;
    }
    __syncthreads();
    int wc = t & 7, wr0 = t >> 3;
    #pragma unroll
    for (int p = 0; p < 2; ++p) {
        int cc = wr0 + p * 32;
        u16 pk[8];
        #pragma unroll
        for (int i = 0; i < 8; ++i)
            pk[i] = f2bf(tile[wc * 8 + i][cc]);
        uint4 v;
        v.x = (u32)pk[0] | ((u32)pk[1] << 16);
        v.y = (u32)pk[2] | ((u32)pk[3] << 16);
        v.z = (u32)pk[4] | ((u32)pk[5] << 16);
        v.w = (u32)pk[6] | ((u32)pk[7] << 16);
        *(uint4*)&dst[(size_t)(c0 + cc) * R + r0 + wc * 8] = v;
    }
}

// ---------------- LN + gate softmax/argmax (wave per token) -----------------
__global__ __launch_bounds__(256) void ln_gate_kernel(
    const float* __restrict__ x, const float* __restrict__ ln_g, const float* __restrict__ ln_b,
    const float* __restrict__ gate_w, const float* __restrict__ gate_b,
    u16* __restrict__ hA, u16* __restrict__ hB,
    int* __restrict__ idxb, float* __restrict__ pbuf)
{
    int wave = threadIdx.x >> 6, lane = threadIdx.x & 63;
    int tok = blockIdx.x * 4 + wave;
    const float* xr = x + (size_t)tok * DD + lane * 8;
    float4 v0 = *(const float4*)xr;
    float4 v1 = *(const float4*)(xr + 4);
    float xs[8] = {v0.x, v0.y, v0.z, v0.w, v1.x, v1.y, v1.z, v1.w};
    float s = 0.f, ss = 0.f;
    #pragma unroll
    for (int i = 0; i < 8; ++i) { s += xs[i]; ss += xs[i] * xs[i]; }
    s = wave_sum(s); ss = wave_sum(ss);
    float mu = s * (1.0f / DD);
    float var = ss * (1.0f / DD) - mu * mu;
    float rstd = rsqrtf(var + 1e-5f);

    #pragma unroll
    for (int br = 0; br < NBR; ++br) {
        u16* hb = br ? hB : hA;
        float part[8] = {0, 0, 0, 0, 0, 0, 0, 0};
        u16 hu[8];
        #pragma unroll
        for (int i = 0; i < 8; ++i) {
            int d = lane * 8 + i;
            float g = ln_g[br * DD + d], b = ln_b[br * DD + d];
            float h = (xs[i] - mu) * rstd * g + b;
            hu[i] = f2bf(h);
            const float* gw = gate_w + ((size_t)br * DD + d) * EE;
            float4 g0 = *(const float4*)gw;
            float4 g1 = *(const float4*)(gw + 4);
            part[0] += h * g0.x; part[1] += h * g0.y; part[2] += h * g0.z; part[3] += h * g0.w;
            part[4] += h * g1.x; part[5] += h * g1.y; part[6] += h * g1.z; part[7] += h * g1.w;
        }
        uint4 pk;
        pk.x = (u32)hu[0] | ((u32)hu[1] << 16);
        pk.y = (u32)hu[2] | ((u32)hu[3] << 16);
        pk.z = (u32)hu[4] | ((u32)hu[5] << 16);
        pk.w = (u32)hu[6] | ((u32)hu[7] << 16);
        *(uint4*)(hb + (size_t)tok * DD + lane * 8) = pk;

        float logit[8];
        #pragma unroll
        for (int e = 0; e < 8; ++e)
            logit[e] = wave_sum(part[e]) + gate_b[br * EE + e];
        float m = logit[0]; int bi = 0;
        #pragma unroll
        for (int e = 1; e < 8; ++e)
            if (logit[e] > m) { m = logit[e]; bi = e; }
        float sum = 0.f;
        #pragma unroll
        for (int e = 0; e < 8; ++e) sum += __expf(logit[e] - m);
        if (lane == 0) {
            idxb[br * NTOK + tok] = bi;
            pbuf[br * NTOK + tok] = 1.0f / sum;
        }
    }
}

// ---------------- routing: LDS histogram, 16 global atomics per block -------
__global__ __launch_bounds__(256) void route_kernel(
    const int* __restrict__ idxb, int* __restrict__ cnt, int* __restrict__ list)
{
    __shared__ int lcnt[GE];
    __shared__ int gbase[GE];
    int tid = threadIdx.x;
    int t = blockIdx.x * 256 + tid;
    if (tid < GE) lcnt[tid] = 0;
    __syncthreads();
    int e0 = idxb[t];
    int e1 = EE + idxb[NTOK + t];
    int r0 = atomicAdd(&lcnt[e0], 1);
    int r1 = atomicAdd(&lcnt[e1], 1);
    __syncthreads();
    if (tid < GE) {
        int c = lcnt[tid];
        gbase[tid] = c ? atomicAdd(&cnt[tid], c) : 0;
    }
    __syncthreads();
    list[(size_t)e0 * NTOK + gbase[e0] + r0] = t;
    list[(size_t)e1 * NTOK + gbase[e1] + r1] = t;
}

// ---------------- tile table (256-row granular) -----------------------------
__global__ void tilestart_kernel(const int* __restrict__ cnt, int* __restrict__ meta)
{
    int lane = threadIdx.x;   // 64 threads
    if (lane < 16) {
        int pbv = 0;
        for (int k = 0; k < lane; ++k) pbv += cnt[k];
        meta[lane] = pbv;
    }
    if (lane == 17) {
        int n = 0;
        for (int k = 0; k < 16; ++k) n += (cnt[k] + 255) >> 8;
        meta[34] = n;
    }
    for (int j = lane; j < MT256; j += 64) {
        int ge = -1, start = 0, tt = 0;
        #pragma unroll
        for (int k = 0; k < 16; ++k) {
            int mt = (cnt[k] + 255) >> 8;
            if (ge < 0) {
                if (j < start + mt) { ge = k; tt = j - start; }
                else start += mt;
            }
        }
        if (ge >= 0) meta[320 + j] = (ge << 20) | tt;
    }
}

// ---------------- 256x256 MFMA GEMM, BK=32, dbuf, counted vmcnt -------------
// 8 waves (2M x 4N), per-wave 128x64 output = 8x4 fragments (LDS-read/MFMA
// ratio 0.375 vs 0.5 for 4x4 — this kernel was LDS-BW-bound at 128^2).
// MODE 0: u[pos] = gelu(h[tok] @ W1[ge] + b1[ge])      A gathered via list
// MODE 1: moe{plane}[tok] = p * (u[pos] @ W2[ge] + b2) A dense, bf16 out
template<int MODE>
__global__ __launch_bounds__(512, 2) void gemm256(
    const u16* __restrict__ A0, const u16* __restrict__ A1,
    const u16* __restrict__ Bt,
    const int* __restrict__ meta, const int* __restrict__ cnt,
    const int* __restrict__ list, const float* __restrict__ pbuf,
    const float* __restrict__ bias,
    u16* __restrict__ uout, u16* __restrict__ moeout)
{
    constexpr int K = (MODE == 1) ? FF : DD;
    constexpr int N = (MODE == 0) ? FF : DD;
    constexpr int NSTEP = K / 32;

    __shared__ __align__(16) u16 As[2][256 * 32];
    __shared__ __align__(16) u16 Bs[2][256 * 32];
    __shared__ int rowtok[256];
    __shared__ float rowp[256];

    int j = blockIdx.y;
    if (j >= meta[34]) return;
    int ev = meta[320 + j];
    int ge = ev >> 20;
    int rb = (ev & 0xfffff) << 8;
    int cnt_e = cnt[ge];
    int pb = meta[ge];
    int ntile = blockIdx.x;

    int tid = threadIdx.x, wave = tid >> 6, lane = tid & 63;
    int wm = wave >> 2, wn = wave & 3;
    int fr = lane & 15, fq = lane >> 4;
    int sc = (lane & 3) ^ ((lane >> 3) & 3);   // pre-swizzled source chunk

    const u16* Bte = Bt + (size_t)ge * FF * DD;

    int ar0 = wave * 32 + (lane >> 2);         // staging rows ar0, ar0+16
    const u16 *aS0, *aS1, *bS0, *bS1;
    if constexpr (MODE == 0) {
        const u16* Ab = (ge >= 8) ? A1 : A0;
        int lb = ge * NTOK;
        int g0 = rb + ar0, g1 = g0 + 16;
        int t0 = (g0 < cnt_e) ? list[lb + g0] : list[lb];
        int t1 = (g1 < cnt_e) ? list[lb + g1] : list[lb];
        aS0 = Ab + (size_t)t0 * K + sc * 8;
        aS1 = Ab + (size_t)t1 * K + sc * 8;
    } else {
        aS0 = A0 + (size_t)(pb + rb + ar0) * K + sc * 8;
        aS1 = aS0 + (size_t)16 * K;            // padding rows read slack (unused)
    }
    {
        int nr = ntile * 256 + ar0;
        bS0 = Bte + (size_t)nr * K + sc * 8;
        bS1 = bS0 + (size_t)16 * K;
    }

    if constexpr (MODE == 1) {
        if (tid < 256) {
            int g = rb + tid;
            int tk = (g < cnt_e) ? list[ge * NTOK + g] : -1;
            rowtok[tid] = tk;
            rowp[tid] = (tk >= 0) ? pbuf[(ge >> 3) * NTOK + tk] : 0.f;
        }
    }

    f32v4 acc[8][4];
    #pragma unroll
    for (int m = 0; m < 8; ++m)
        #pragma unroll
        for (int n = 0; n < 4; ++n)
            acc[m][n] = (f32v4){0.f, 0.f, 0.f, 0.f};

    int ch = fq ^ ((fr >> 1) & 3);             // swizzled read chunk
    int dA = wave * 1024;                      // u16 offset: 32 rows per wave

    // ---- prologue: stage step 0 into buf 0 ----
    gload16(aS0, &As[0][dA]);
    gload16(aS1, &As[0][dA + 512]);
    gload16(bS0, &Bs[0][dA]);
    gload16(bS1, &Bs[0][dA + 512]);
    aS0 += 32; aS1 += 32; bS0 += 32; bS1 += 32;

    for (int t = 0; t < NSTEP; ++t) {
        const int cur = t & 1;
        if (t + 1 < NSTEP) {
            gload16(aS0, &As[cur ^ 1][dA]);
            gload16(aS1, &As[cur ^ 1][dA + 512]);
            gload16(bS0, &Bs[cur ^ 1][dA]);
            gload16(bS1, &Bs[cur ^ 1][dA + 512]);
            aS0 += 32; aS1 += 32; bS0 += 32; bS1 += 32;
            ASM_VMCNT4;    // step t's 4 loads landed; step t+1's 4 in flight
        } else {
            ASM_VMCNT0;
        }
        bar();

        bf16v8 bf[4];
        #pragma unroll
        for (int n = 0; n < 4; ++n)
            bf[n] = *(const bf16v8*)&Bs[cur][(wn * 64 + n * 16 + fr) * 32 + ch * 8];
        #pragma unroll
        for (int m = 0; m < 8; ++m) {
            bf16v8 af = *(const bf16v8*)&As[cur][(wm * 128 + m * 16 + fr) * 32 + ch * 8];
            #pragma unroll
            for (int n = 0; n < 4; ++n)
                acc[m][n] = __builtin_amdgcn_mfma_f32_16x16x32_bf16(af, bf[n], acc[m][n], 0, 0, 0);
        }
        bar();
    }

    // ---- epilogue (C/D frag: col = lane&15, row = fq*4 + reg) ----
    #pragma unroll
    for (int m = 0; m < 8; ++m) {
        #pragma unroll
        for (int n = 0; n < 4; ++n) {
            int col = ntile * 256 + wn * 64 + n * 16 + fr;
            float bn = bias[(size_t)ge * N + col];
            #pragma unroll
            for (int r = 0; r < 4; ++r) {
                int rr = wm * 128 + m * 16 + fq * 4 + r;
                float v = acc[m][n][r] + bn;
                if constexpr (MODE == 0) {
                    if (rb + rr < cnt_e)
                        uout[(size_t)(pb + rb + rr) * FF + col] = f2bf(gelu_tanh(v));
                } else {
                    int tok = rowtok[rr];
                    if (tok >= 0)
                        moeout[((size_t)(ge >> 3) * NTOK + tok) * DD + col] =
                            f2bf(v * rowp[rr]);
                }
            }
        }
    }
}

// ---------------- 128x128 GEMM (output projection only) ---------------------
// dout = xres + A @ owt + out_b  (A dense bf16, f32 out)
__global__ __launch_bounds__(256, 3) void gemm_out(
    const u16* __restrict__ A0, const u16* __restrict__ Bt,
    const float* __restrict__ bias,
    const float* __restrict__ xres, float* __restrict__ dout)
{
    constexpr int K = DD;
    constexpr int NSTEP = K / 32;

    __shared__ __align__(16) u16 As[2][128 * 32];
    __shared__ __align__(16) u16 Bs[2][128 * 32];

    int ntile = blockIdx.x;
    int rb = blockIdx.y * 128;

    int tid = threadIdx.x, wave = tid >> 6, lane = tid & 63;
    int wm = wave >> 1, wn = wave & 1;
    int fr = lane & 15, fq = lane >> 4;
    int r0 = wave * 16 + (lane >> 2);
    int sc = (lane & 3) ^ ((lane >> 3) & 3);

    const u16 *aSrc0, *aSrc1, *bSrc0, *bSrc1;
    aSrc0 = A0 + (size_t)(rb + r0) * K + sc * 8;
    aSrc1 = A0 + (size_t)(rb + r0 + 64) * K + sc * 8;
    {
        int nrow = ntile * 128 + r0;
        bSrc0 = Bt + (size_t)nrow * K + sc * 8;
        bSrc1 = Bt + (size_t)(nrow + 64) * K + sc * 8;
    }

    f32v4 acc[4][4];
    #pragma unroll
    for (int mi = 0; mi < 4; ++mi)
        #pragma unroll
        for (int ni = 0; ni < 4; ++ni)
            acc[mi][ni] = (f32v4){0.f, 0.f, 0.f, 0.f};

    int ch = fq ^ ((fr >> 1) & 3);

    gload16(aSrc0, &As[0][wave * 512]);
    gload16(aSrc1, &As[0][2048 + wave * 512]);
    gload16(bSrc0, &Bs[0][wave * 512]);
    gload16(bSrc1, &Bs[0][2048 + wave * 512]);
    aSrc0 += 32; aSrc1 += 32; bSrc0 += 32; bSrc1 += 32;

    #pragma unroll 2
    for (int t = 0; t < NSTEP; ++t) {
        const int cur = t & 1;
        if (t + 1 < NSTEP) {
            gload16(aSrc0, &As[cur ^ 1][wave * 512]);
            gload16(aSrc1, &As[cur ^ 1][2048 + wave * 512]);
            gload16(bSrc0, &Bs[cur ^ 1][wave * 512]);
            gload16(bSrc1, &Bs[cur ^ 1][2048 + wave * 512]);
            aSrc0 += 32; aSrc1 += 32; bSrc0 += 32; bSrc1 += 32;
            ASM_VMCNT4;
        } else {
            ASM_VMCNT0;
        }
        bar();

        bf16v8 af[4], bfr[4];
        #pragma unroll
        for (int mi = 0; mi < 4; ++mi)
            af[mi] = *(const bf16v8*)&As[cur][(wm * 64 + mi * 16 + fr) * 32 + ch * 8];
        #pragma unroll
        for (int ni = 0; ni < 4; ++ni)
            bfr[ni] = *(const bf16v8*)&Bs[cur][(wn * 64 + ni * 16 + fr) * 32 + ch * 8];
        #pragma unroll
        for (int mi = 0; mi < 4; ++mi)
            #pragma unroll
            for (int ni = 0; ni < 4; ++ni)
                acc[mi][ni] = __builtin_amdgcn_mfma_f32_16x16x32_bf16(
                    af[mi], bfr[ni], acc[mi][ni], 0, 0, 0);
        bar();
    }

    #pragma unroll
    for (int mi = 0; mi < 4; ++mi) {
        #pragma unroll
        for (int ni = 0; ni < 4; ++ni) {
            int col = ntile * 128 + wn * 64 + ni * 16 + fr;
            float bn = bias[col];
            #pragma unroll
            for (int r = 0; r < 4; ++r) {
                int rr = wm * 64 + mi * 16 + fq * 4 + r;
                size_t o = (size_t)(rb + rr) * DD + col;
                dout[o] = xres[o] + acc[mi][ni][r] + bn;
            }
        }
    }
}

// ---------------- stylize: LN((moe0+moe1)/2)*(1+scale)+shift -> silu -> bf16
__global__ __launch_bounds__(256) void stylize_kernel(
    const u16* __restrict__ moe, const float* __restrict__ eo,
    const float* __restrict__ sn_g, const float* __restrict__ sn_b,
    u16* __restrict__ sbuf)
{
    int wave = threadIdx.x >> 6, lane = threadIdx.x & 63;
    int tok = blockIdx.x * 4 + wave;
    int b = tok / TT;
    const u16* mr = moe + (size_t)tok * DD + lane * 8;
    const u16* mr2 = mr + (size_t)NTOK * DD;
    uint4 pa = *(const uint4*)mr;
    uint4 pb = *(const uint4*)mr2;
    float os[8];
    os[0] = (bf2f(pa.x & 0xffff) + bf2f(pb.x & 0xffff)) * 0.5f;
    os[1] = (bf2f(pa.x >> 16)    + bf2f(pb.x >> 16))    * 0.5f;
    os[2] = (bf2f(pa.y & 0xffff) + bf2f(pb.y & 0xffff)) * 0.5f;
    os[3] = (bf2f(pa.y >> 16)    + bf2f(pb.y >> 16))    * 0.5f;
    os[4] = (bf2f(pa.z & 0xffff) + bf2f(pb.z & 0xffff)) * 0.5f;
    os[5] = (bf2f(pa.z >> 16)    + bf2f(pb.z >> 16))    * 0.5f;
    os[6] = (bf2f(pa.w & 0xffff) + bf2f(pb.w & 0xffff)) * 0.5f;
    os[7] = (bf2f(pa.w >> 16)    + bf2f(pb.w >> 16))    * 0.5f;
    float s = 0.f, ss = 0.f;
    #pragma unroll
    for (int i = 0; i < 8; ++i) { s += os[i]; ss += os[i] * os[i]; }
    s = wave_sum(s); ss = wave_sum(ss);
    float mu = s * (1.0f / DD);
    float var = ss * (1.0f / DD) - mu * mu;
    float rstd = rsqrtf(var + 1e-5f);
    u16 hu[8];
    #pragma unroll
    for (int i = 0; i < 8; ++i) {
        int d = lane * 8 + i;
        float h = (os[i] - mu) * rstd * sn_g[d] + sn_b[d];
        float scv = eo[(size_t)b * 1024 + d];
        float shv = eo[(size_t)b * 1024 + DD + d];
        h = h * (1.0f + scv) + shv;
        hu[i] = f2bf(silu(h));
    }
    uint4 pk;
    pk.x = (u32)hu[0] | ((u32)hu[1] << 16);
    pk.y = (u32)hu[2] | ((u32)hu[3] << 16);
    pk.z = (u32)hu[4] | ((u32)hu[5] << 16);
    pk.w = (u32)hu[6] | ((u32)hu[7] << 16);
    *(uint4*)(sbuf + (size_t)tok * DD + lane * 8) = pk;
}

// ---------------- host ----------------
extern "C" void kernel_launch(void* const* d_in, const int* in_sizes, int n_in,
                              void* d_out, int out_size, void* d_ws, size_t ws_size,
                              hipStream_t stream)
{
    const float* x      = (const float*)d_in[0];
    const float* emb    = (const float*)d_in[1];
    const float* ln_g   = (const float*)d_in[2];
    const float* ln_b   = (const float*)d_in[3];
    const float* gate_w = (const float*)d_in[4];
    const float* gate_b = (const float*)d_in[5];
    const float* w1     = (const float*)d_in[6];
    const float* b1     = (const float*)d_in[7];
    const float* w2     = (const float*)d_in[8];
    const float* b2     = (const float*)d_in[9];
    const float* emb_w  = (const float*)d_in[10];
    const float* emb_b  = (const float*)d_in[11];
    const float* sn_g   = (const float*)d_in[12];
    const float* sn_b   = (const float*)d_in[13];
    const float* out_w  = (const float*)d_in[14];
    const float* out_b  = (const float*)d_in[15];
    (void)n_in; (void)in_sizes; (void)out_size; (void)ws_size;

    const size_t szW    = (size_t)GE * FF * DD * 2;             // 33.5 MB each
    const size_t szOwt  = (size_t)DD * DD * 2;
    const size_t szH    = (size_t)NTOK * DD * 2;                // 12.85 MB
    const size_t szEo   = (size_t)BB * 2 * DD * 4;
    const size_t szP    = (size_t)NBR * NTOK * 4;
    const size_t szCnt  = 256, szMeta = 4096;
    const size_t szList = (size_t)GE * NTOK * 4;
    const size_t szU    = ((size_t)2 * NTOK + 512) * FF * 2;    // 103 MB + slack
    const size_t szM    = (size_t)2 * NTOK * DD * 2;            // 25.7 MB (bf16)

    auto align256 = [](size_t v) { return (v + 255) & ~(size_t)255; };
    char* w = (char*)d_ws;
    size_t off = 0;
    auto take = [&](size_t bytes) -> void* {
        void* p = w + off;
        off = align256(off + bytes);
        return p;
    };
    u16*   w1t  = (u16*)take(szW);
    u16*   w2t  = (u16*)take(szW);
    u16*   owt  = (u16*)take(szOwt);
    u16*   hA   = (u16*)take(szH);       // reused as sbuf
    u16*   hB   = (u16*)take(szH);
    float* eo   = (float*)take(szEo);
    float* pbuf = (float*)take(szP);
    int*   idxb = (int*)take(szP);
    int*   cnt  = (int*)take(szCnt);
    int*   meta = (int*)take(szMeta);
    int*   list = (int*)take(szList);
    u16*   ubuf = (u16*)take(szU);
    u16*   moe  = (u16*)take(szM);

    // 1. weight transposes + eo + cnt init (one dispatch)
    mtrans_eo_kernel<<<8320, 256, 0, stream>>>(w1, w1t, w2, w2t, out_w, owt,
                                               emb, emb_w, emb_b, eo, cnt);

    // 2. LN + gate
    ln_gate_kernel<<<NTOK / 4, 256, 0, stream>>>(x, ln_g, ln_b, gate_w, gate_b,
                                                 hA, hB, idxb, pbuf);

    // 3. routing (LDS histogram) + tile table
    route_kernel<<<NTOK / 256, 256, 0, stream>>>(idxb, cnt, list);
    tilestart_kernel<<<1, 64, 0, stream>>>(cnt, meta);

    // 4. expert FFN (256^2 tiles, ntile-fastest)
    gemm256<0><<<dim3(FF / 256, MT256), 512, 0, stream>>>(
        hA, hB, w1t, meta, cnt, list, nullptr, b1, ubuf, nullptr);
    gemm256<1><<<dim3(DD / 256, MT256), 512, 0, stream>>>(
        ubuf, nullptr, w2t, meta, cnt, list, pbuf, b2, nullptr, moe);

    // 5. stylization + output projection + residual
    stylize_kernel<<<NTOK / 4, 256, 0, stream>>>(moe, eo, sn_g, sn_b, hA);
    gemm_out<<<dim3(DD / 128, NTOK / 128), 256, 0, stream>>>(
        hA, owt, out_b, x, (float*)d_out);
}

// Round 11
// 339.241 us; speedup vs baseline: 1.1714x; 1.1714x over previous
//
#include <hip/hip_runtime.h>
#include <hip/hip_bf16.h>

typedef unsigned short u16;
typedef unsigned int u32;

typedef short bf16v8 __attribute__((ext_vector_type(8)));
typedef float f32v4 __attribute__((ext_vector_type(4)));

// ---------------- problem constants ----------------
constexpr int BB   = 64;
constexpr int TT   = 196;
constexpr int NTOK = BB * TT;   // 12544
constexpr int DD   = 512;
constexpr int FF   = 2048;
constexpr int EE   = 8;
constexpr int NBR  = 2;
constexpr int GE   = NBR * EE;  // 16 global experts
constexpr int MT128 = 212;      // >= max total 128-row tiles (<=210)
constexpr int NB_FRONT = 8320 + NTOK / 4;   // transposes+eo+ln_gate blocks

// meta: [0..15] u-row base (cumsum); [33] n128; [64..64+n128) (ge<<20)|tile
__device__ __forceinline__ u16 f2bf(float f) {
    union { float f; u32 u; } v; v.f = f;
    u32 r = v.u + 0x7fffu + ((v.u >> 16) & 1u);
    return (u16)(r >> 16);
}

__device__ __forceinline__ float bf2f(u32 u) {
    union { u32 u; float f; } v; v.u = u << 16; return v.f;
}

__device__ __forceinline__ float wave_sum(float v) {
    #pragma unroll
    for (int m = 32; m > 0; m >>= 1) v += __shfl_xor(v, m, 64);
    return v;
}

// tanh-approx gelu via sigmoid: gelu(v) = v * sigmoid(1.596v + 0.0714v^3)
__device__ __forceinline__ float gelu_tanh(float v) {
    float y = 1.595769122f * v + 0.071354816f * (v * v * v);
    return v / (1.0f + __expf(-y));
}

__device__ __forceinline__ float silu(float v) {
    return v / (1.0f + __expf(-v));
}

__device__ __forceinline__ void gload16(const u16* g, u16* l) {
    typedef const __attribute__((address_space(1))) unsigned gv_t;
    typedef __attribute__((address_space(3))) unsigned lv_t;
    __builtin_amdgcn_global_load_lds((gv_t*)g, (lv_t*)l, 16, 0, 0);
}

__device__ __forceinline__ void bar() {
    asm volatile("" ::: "memory");
    __builtin_amdgcn_s_barrier();
    asm volatile("" ::: "memory");
}

#define ASM_VMCNT4 asm volatile("s_waitcnt vmcnt(4)" ::: "memory")
#define ASM_VMCNT0 asm volatile("s_waitcnt vmcnt(0)" ::: "memory")
#define ASM_LGKM0  asm volatile("s_waitcnt lgkmcnt(0)" ::: "memory")

// ---------------- merged front: transposes + eo GEMM + cnt init + ln_gate ---
// grid: [0,4096) w1 64x64 tiles; [4096,8192) w2; [8192,8256) out_w;
//       [8256,8320) eo; [8320, 8320+NTOK/4) ln_gate (4 tokens/block)
__global__ __launch_bounds__(256) void front_kernel(
    const float* __restrict__ w1, u16* __restrict__ w1t,
    const float* __restrict__ w2, u16* __restrict__ w2t,
    const float* __restrict__ ow, u16* __restrict__ owt,
    const float* __restrict__ emb, const float* __restrict__ emb_w,
    const float* __restrict__ emb_b, float* __restrict__ eo,
    int* __restrict__ cnt,
    const float* __restrict__ x, const float* __restrict__ ln_g,
    const float* __restrict__ ln_b, const float* __restrict__ gate_w,
    const float* __restrict__ gate_b,
    u16* __restrict__ hA, u16* __restrict__ hB,
    int* __restrict__ idxb, float* __restrict__ pbuf)
{
    __shared__ float tile[64][69];
    __shared__ float se[4][DD];
    int id = blockIdx.x;
    int t = threadIdx.x;

    if (id >= 8320) {              // ---- ln_gate: 4 tokens per block ----
        int wave = t >> 6, lane = t & 63;
        int tok = (id - 8320) * 4 + wave;
        const float* xr = x + (size_t)tok * DD + lane * 8;
        float4 v0 = *(const float4*)xr;
        float4 v1 = *(const float4*)(xr + 4);
        float xs[8] = {v0.x, v0.y, v0.z, v0.w, v1.x, v1.y, v1.z, v1.w};
        float s = 0.f, ss = 0.f;
        #pragma unroll
        for (int i = 0; i < 8; ++i) { s += xs[i]; ss += xs[i] * xs[i]; }
        s = wave_sum(s); ss = wave_sum(ss);
        float mu = s * (1.0f / DD);
        float var = ss * (1.0f / DD) - mu * mu;
        float rstd = rsqrtf(var + 1e-5f);

        #pragma unroll
        for (int br = 0; br < NBR; ++br) {
            u16* hb = br ? hB : hA;
            float part[8] = {0, 0, 0, 0, 0, 0, 0, 0};
            u16 hu[8];
            #pragma unroll
            for (int i = 0; i < 8; ++i) {
                int d = lane * 8 + i;
                float g = ln_g[br * DD + d], b = ln_b[br * DD + d];
                float h = (xs[i] - mu) * rstd * g + b;
                hu[i] = f2bf(h);
                const float* gw = gate_w + ((size_t)br * DD + d) * EE;
                float4 g0 = *(const float4*)gw;
                float4 g1 = *(const float4*)(gw + 4);
                part[0] += h * g0.x; part[1] += h * g0.y; part[2] += h * g0.z; part[3] += h * g0.w;
                part[4] += h * g1.x; part[5] += h * g1.y; part[6] += h * g1.z; part[7] += h * g1.w;
            }
            uint4 pk;
            pk.x = (u32)hu[0] | ((u32)hu[1] << 16);
            pk.y = (u32)hu[2] | ((u32)hu[3] << 16);
            pk.z = (u32)hu[4] | ((u32)hu[5] << 16);
            pk.w = (u32)hu[6] | ((u32)hu[7] << 16);
            *(uint4*)(hb + (size_t)tok * DD + lane * 8) = pk;

            float logit[8];
            #pragma unroll
            for (int e = 0; e < 8; ++e)
                logit[e] = wave_sum(part[e]) + gate_b[br * EE + e];
            float m = logit[0]; int bi = 0;
            #pragma unroll
            for (int e = 1; e < 8; ++e)
                if (logit[e] > m) { m = logit[e]; bi = e; }
            float sum = 0.f;
            #pragma unroll
            for (int e = 0; e < 8; ++e) sum += __expf(logit[e] - m);
            if (lane == 0) {
                idxb[br * NTOK + tok] = bi;
                pbuf[br * NTOK + tok] = 1.0f / sum;
            }
        }
        return;
    }

    if (id >= 8256) {              // ---- eo: silu(emb) @ emb_w + emb_b ----
        int id2 = id - 8256;
        int cg = id2 & 3, bg = id2 >> 2;
        int b0 = bg * 4;
        int c0 = cg * 256 + t;
        for (int i = t; i < 4 * DD; i += 256) {
            int b = i >> 9, d = i & (DD - 1);
            se[b][d] = silu(emb[(size_t)(b0 + b) * DD + d]);
        }
        __syncthreads();
        float acc[4] = {0, 0, 0, 0};
        for (int k = 0; k < DD; ++k) {
            float wv = emb_w[(size_t)k * 1024 + c0];
            #pragma unroll
            for (int b = 0; b < 4; ++b) acc[b] += se[b][k] * wv;
        }
        float bb = emb_b[c0];
        #pragma unroll
        for (int b = 0; b < 4; ++b)
            eo[(size_t)(b0 + b) * 1024 + c0] = acc[b] + bb;
        return;
    }

    if (id == 0 && t < 16) cnt[t] = 0;

    const float* src; u16* dst; int R, C, rt, ct;
    if (id < 4096) {
        int e = id >> 8, rem = id & 255;
        R = DD; C = FF; rt = rem >> 5; ct = rem & 31;
        src = w1 + (size_t)e * R * C; dst = w1t + (size_t)e * R * C;
    } else if (id < 8192) {
        int e = (id - 4096) >> 8, rem = (id - 4096) & 255;
        R = FF; C = DD; rt = rem >> 3; ct = rem & 7;
        src = w2 + (size_t)e * R * C; dst = w2t + (size_t)e * R * C;
    } else {
        int rem = id - 8192;
        R = DD; C = DD; rt = rem >> 3; ct = rem & 7;
        src = ow; dst = owt;
    }
    int tx = t & 15, ty = t >> 4;
    int r0 = rt * 64, c0 = ct * 64;
    #pragma unroll
    for (int j = 0; j < 4; ++j) {
        int row = ty + j * 16;
        float4 v = *(const float4*)&src[(size_t)(r0 + row) * C + c0 + tx * 4];
        tile[row][tx * 4 + 0] = v.x;
        tile[row][tx * 4 + 1] = v.y;
        tile[row][tx * 4 + 2] = v.z;
        tile[row][tx * 4 + 3] = v.w;
    }
    __syncthreads();
    int wc = t & 7, wr0 = t >> 3;
    #pragma unroll
    for (int p = 0; p < 2; ++p) {
        int cc = wr0 + p * 32;
        u16 pk[8];
        #pragma unroll
        for (int i = 0; i < 8; ++i)
            pk[i] = f2bf(tile[wc * 8 + i][cc]);
        uint4 v;
        v.x = (u32)pk[0] | ((u32)pk[1] << 16);
        v.y = (u32)pk[2] | ((u32)pk[3] << 16);
        v.z = (u32)pk[4] | ((u32)pk[5] << 16);
        v.w = (u32)pk[6] | ((u32)pk[7] << 16);
        *(uint4*)&dst[(size_t)(c0 + cc) * R + r0 + wc * 8] = v;
    }
}

// ---------------- routing: LDS histogram, 16 global atomics per block -------
__global__ __launch_bounds__(256) void route_kernel(
    const int* __restrict__ idxb, int* __restrict__ cnt, int* __restrict__ list)
{
    __shared__ int lcnt[GE];
    __shared__ int gbase[GE];
    int tid = threadIdx.x;
    int t = blockIdx.x * 256 + tid;
    if (tid < GE) lcnt[tid] = 0;
    __syncthreads();
    int e0 = idxb[t];
    int e1 = EE + idxb[NTOK + t];
    int r0 = atomicAdd(&lcnt[e0], 1);
    int r1 = atomicAdd(&lcnt[e1], 1);
    __syncthreads();
    if (tid < GE) {
        int c = lcnt[tid];
        gbase[tid] = c ? atomicAdd(&cnt[tid], c) : 0;
    }
    __syncthreads();
    list[(size_t)e0 * NTOK + gbase[e0] + r0] = t;
    list[(size_t)e1 * NTOK + gbase[e1] + r1] = t;
}

// ---------------- tile table (128-row granular) -----------------------------
__global__ void tilestart_kernel(const int* __restrict__ cnt, int* __restrict__ meta)
{
    int lane = threadIdx.x;   // 64 threads
    if (lane < 16) {
        int pbv = 0;
        for (int k = 0; k < lane; ++k) pbv += cnt[k];
        meta[lane] = pbv;
    }
    if (lane == 16) {
        int n = 0;
        for (int k = 0; k < 16; ++k) n += (cnt[k] + 127) >> 7;
        meta[33] = n;
    }
    for (int j = lane; j < MT128; j += 64) {
        int ge = -1, start = 0, tt = 0;
        #pragma unroll
        for (int k = 0; k < 16; ++k) {
            int mt = (cnt[k] + 127) >> 7;
            if (ge < 0) {
                if (j < start + mt) { ge = k; tt = j - start; }
                else start += mt;
            }
        }
        if (ge >= 0) meta[64 + j] = (ge << 20) | tt;
    }
}

// ---------------- 128x128 MFMA GEMM, BK=32, dbuf, counted vmcnt, 4 blk/CU ---
// MODE 0: u[pos] = gelu(h[tok] @ W1[ge] + b1[ge])      A gathered via list
// MODE 1: moe{plane}[tok] = p * (u[pos] @ W2[ge] + b2) A dense, bf16 out
// grid: (ntile, tileidx) — ntile fastest for A-tile L2 reuse
template<int MODE>
__global__ __launch_bounds__(256, 4) void gemm_tile(
    const u16* __restrict__ A0, const u16* __restrict__ A1,
    const u16* __restrict__ Bt,
    const int* __restrict__ meta, const int* __restrict__ cnt,
    const int* __restrict__ list, const float* __restrict__ pbuf,
    const float* __restrict__ bias,
    u16* __restrict__ uout, u16* __restrict__ moeout)
{
    constexpr int K = (MODE == 1) ? FF : DD;
    constexpr int N = (MODE == 0) ? FF : DD;
    constexpr int NSTEP = K / 32;

    __shared__ __align__(16) u16 As[2][128 * 32];
    __shared__ __align__(16) u16 Bs[2][128 * 32];
    __shared__ int rowtok[128];
    __shared__ float rowp[128];

    int ntile = blockIdx.x;
    int j = blockIdx.y;
    if (j >= meta[33]) return;
    int ev = meta[64 + j];
    int ge = ev >> 20;
    int rb = (ev & 0xfffff) << 7;
    int cnt_e = cnt[ge];
    int pb = meta[ge];

    int tid = threadIdx.x, wave = tid >> 6, lane = tid & 63;
    int wm = wave >> 1, wn = wave & 1;
    int fr = lane & 15, fq = lane >> 4;
    int r0 = wave * 16 + (lane >> 2);
    int sc = (lane & 3) ^ ((lane >> 3) & 3);   // swizzled source chunk (bank fix)

    const u16* Abase;
    if constexpr (MODE == 0) Abase = (ge >= 8) ? A1 : A0;
    else                     Abase = A0;
    const u16* Bte = Bt + (size_t)ge * FF * DD;

    const u16 *aSrc0, *aSrc1, *bSrc0, *bSrc1;
    if constexpr (MODE == 0) {
        int lb = ge * NTOK;
        int g0 = rb + r0, g1 = g0 + 64;
        int t0 = (g0 < cnt_e) ? list[lb + g0] : list[lb];
        int t1 = (g1 < cnt_e) ? list[lb + g1] : list[lb];
        aSrc0 = Abase + (size_t)t0 * K + sc * 8;
        aSrc1 = Abase + (size_t)t1 * K + sc * 8;
    } else {
        size_t base = (size_t)(pb + rb);
        aSrc0 = Abase + (base + r0) * (size_t)K + sc * 8;
        aSrc1 = Abase + (base + r0 + 64) * (size_t)K + sc * 8;
    }
    {
        int nrow = ntile * 128 + r0;
        bSrc0 = Bte + (size_t)nrow * K + sc * 8;
        bSrc1 = Bte + (size_t)(nrow + 64) * K + sc * 8;
    }

    if constexpr (MODE == 1) {
        if (tid < 128) {
            int g = rb + tid;
            int tk = (g < cnt_e) ? list[ge * NTOK + g] : -1;
            rowtok[tid] = tk;
            rowp[tid] = (tk >= 0) ? pbuf[(ge >> 3) * NTOK + tk] : 0.f;
        }
        ASM_LGKM0;
    }

    f32v4 acc[4][4];
    #pragma unroll
    for (int mi = 0; mi < 4; ++mi)
        #pragma unroll
        for (int ni = 0; ni < 4; ++ni)
            acc[mi][ni] = (f32v4){0.f, 0.f, 0.f, 0.f};

    int ch = fq ^ ((fr >> 1) & 3);             // swizzled read chunk (bank fix)

    // ---- prologue: stage step 0 into buf 0 ----
    gload16(aSrc0, &As[0][wave * 512]);
    gload16(aSrc1, &As[0][2048 + wave * 512]);
    gload16(bSrc0, &Bs[0][wave * 512]);
    gload16(bSrc1, &Bs[0][2048 + wave * 512]);
    aSrc0 += 32; aSrc1 += 32; bSrc0 += 32; bSrc1 += 32;

    #pragma unroll 2
    for (int t = 0; t < NSTEP; ++t) {
        const int cur = t & 1;
        if (t + 1 < NSTEP) {
            gload16(aSrc0, &As[cur ^ 1][wave * 512]);
            gload16(aSrc1, &As[cur ^ 1][2048 + wave * 512]);
            gload16(bSrc0, &Bs[cur ^ 1][wave * 512]);
            gload16(bSrc1, &Bs[cur ^ 1][2048 + wave * 512]);
            aSrc0 += 32; aSrc1 += 32; bSrc0 += 32; bSrc1 += 32;
            ASM_VMCNT4;    // step t's 4 loads landed; step t+1's 4 in flight
        } else {
            ASM_VMCNT0;
        }
        bar();

        bf16v8 af[4], bfr[4];
        #pragma unroll
        for (int mi = 0; mi < 4; ++mi)
            af[mi] = *(const bf16v8*)&As[cur][(wm * 64 + mi * 16 + fr) * 32 + ch * 8];
        #pragma unroll
        for (int ni = 0; ni < 4; ++ni)
            bfr[ni] = *(const bf16v8*)&Bs[cur][(wn * 64 + ni * 16 + fr) * 32 + ch * 8];
        #pragma unroll
        for (int mi = 0; mi < 4; ++mi)
            #pragma unroll
            for (int ni = 0; ni < 4; ++ni)
                acc[mi][ni] = __builtin_amdgcn_mfma_f32_16x16x32_bf16(
                    af[mi], bfr[ni], acc[mi][ni], 0, 0, 0);
        bar();
    }

    // ---- epilogue (C/D frag: col = lane&15, row = fq*4 + reg) ----
    #pragma unroll
    for (int mi = 0; mi < 4; ++mi) {
        #pragma unroll
        for (int ni = 0; ni < 4; ++ni) {
            int col = ntile * 128 + wn * 64 + ni * 16 + fr;
            float bn = bias[(size_t)ge * N + col];
            #pragma unroll
            for (int r = 0; r < 4; ++r) {
                int rr = wm * 64 + mi * 16 + fq * 4 + r;
                float v = acc[mi][ni][r] + bn;
                if constexpr (MODE == 0) {
                    if (rb + rr < cnt_e)
                        uout[(size_t)(pb + rb + rr) * FF + col] = f2bf(gelu_tanh(v));
                } else {
                    int tok = rowtok[rr];
                    if (tok >= 0)
                        moeout[((size_t)(ge >> 3) * NTOK + tok) * DD + col] =
                            f2bf(v * rowp[rr]);
                }
            }
        }
    }
}

// ---------------- 128x128 GEMM (output projection only) ---------------------
// dout = xres + A @ owt + out_b  (A dense bf16, f32 out)
__global__ __launch_bounds__(256, 4) void gemm_out(
    const u16* __restrict__ A0, const u16* __restrict__ Bt,
    const float* __restrict__ bias,
    const float* __restrict__ xres, float* __restrict__ dout)
{
    constexpr int K = DD;
    constexpr int NSTEP = K / 32;

    __shared__ __align__(16) u16 As[2][128 * 32];
    __shared__ __align__(16) u16 Bs[2][128 * 32];

    int ntile = blockIdx.x;
    int rb = blockIdx.y * 128;

    int tid = threadIdx.x, wave = tid >> 6, lane = tid & 63;
    int wm = wave >> 1, wn = wave & 1;
    int fr = lane & 15, fq = lane >> 4;
    int r0 = wave * 16 + (lane >> 2);
    int sc = (lane & 3) ^ ((lane >> 3) & 3);

    const u16 *aSrc0, *aSrc1, *bSrc0, *bSrc1;
    aSrc0 = A0 + (size_t)(rb + r0) * K + sc * 8;
    aSrc1 = A0 + (size_t)(rb + r0 + 64) * K + sc * 8;
    {
        int nrow = ntile * 128 + r0;
        bSrc0 = Bt + (size_t)nrow * K + sc * 8;
        bSrc1 = Bt + (size_t)(nrow + 64) * K + sc * 8;
    }

    f32v4 acc[4][4];
    #pragma unroll
    for (int mi = 0; mi < 4; ++mi)
        #pragma unroll
        for (int ni = 0; ni < 4; ++ni)
            acc[mi][ni] = (f32v4){0.f, 0.f, 0.f, 0.f};

    int ch = fq ^ ((fr >> 1) & 3);

    gload16(aSrc0, &As[0][wave * 512]);
    gload16(aSrc1, &As[0][2048 + wave * 512]);
    gload16(bSrc0, &Bs[0][wave * 512]);
    gload16(bSrc1, &Bs[0][2048 + wave * 512]);
    aSrc0 += 32; aSrc1 += 32; bSrc0 += 32; bSrc1 += 32;

    #pragma unroll 2
    for (int t = 0; t < NSTEP; ++t) {
        const int cur = t & 1;
        if (t + 1 < NSTEP) {
            gload16(aSrc0, &As[cur ^ 1][wave * 512]);
            gload16(aSrc1, &As[cur ^ 1][2048 + wave * 512]);
            gload16(bSrc0, &Bs[cur ^ 1][wave * 512]);
            gload16(bSrc1, &Bs[cur ^ 1][2048 + wave * 512]);
            aSrc0 += 32; aSrc1 += 32; bSrc0 += 32; bSrc1 += 32;
            ASM_VMCNT4;
        } else {
            ASM_VMCNT0;
        }
        bar();

        bf16v8 af[4], bfr[4];
        #pragma unroll
        for (int mi = 0; mi < 4; ++mi)
            af[mi] = *(const bf16v8*)&As[cur][(wm * 64 + mi * 16 + fr) * 32 + ch * 8];
        #pragma unroll
        for (int ni = 0; ni < 4; ++ni)
            bfr[ni] = *(const bf16v8*)&Bs[cur][(wn * 64 + ni * 16 + fr) * 32 + ch * 8];
        #pragma unroll
        for (int mi = 0; mi < 4; ++mi)
            #pragma unroll
            for (int ni = 0; ni < 4; ++ni)
                acc[mi][ni] = __builtin_amdgcn_mfma_f32_16x16x32_bf16(
                    af[mi], bfr[ni], acc[mi][ni], 0, 0, 0);
        bar();
    }

    #pragma unroll
    for (int mi = 0; mi < 4; ++mi) {
        #pragma unroll
        for (int ni = 0; ni < 4; ++ni) {
            int col = ntile * 128 + wn * 64 + ni * 16 + fr;
            float bn = bias[col];
            #pragma unroll
            for (int r = 0; r < 4; ++r) {
                int rr = wm * 64 + mi * 16 + fq * 4 + r;
                size_t o = (size_t)(rb + rr) * DD + col;
                dout[o] = xres[o] + acc[mi][ni][r] + bn;
            }
        }
    }
}

// ---------------- stylize: LN((moe0+moe1)/2)*(1+scale)+shift -> silu -> bf16
__global__ __launch_bounds__(256) void stylize_kernel(
    const u16* __restrict__ moe, const float* __restrict__ eo,
    const float* __restrict__ sn_g, const float* __restrict__ sn_b,
    u16* __restrict__ sbuf)
{
    int wave = threadIdx.x >> 6, lane = threadIdx.x & 63;
    int tok = blockIdx.x * 4 + wave;
    int b = tok / TT;
    const u16* mr = moe + (size_t)tok * DD + lane * 8;
    const u16* mr2 = mr + (size_t)NTOK * DD;
    uint4 pa = *(const uint4*)mr;
    uint4 pb = *(const uint4*)mr2;
    float os[8];
    os[0] = (bf2f(pa.x & 0xffff) + bf2f(pb.x & 0xffff)) * 0.5f;
    os[1] = (bf2f(pa.x >> 16)    + bf2f(pb.x >> 16))    * 0.5f;
    os[2] = (bf2f(pa.y & 0xffff) + bf2f(pb.y & 0xffff)) * 0.5f;
    os[3] = (bf2f(pa.y >> 16)    + bf2f(pb.y >> 16))    * 0.5f;
    os[4] = (bf2f(pa.z & 0xffff) + bf2f(pb.z & 0xffff)) * 0.5f;
    os[5] = (bf2f(pa.z >> 16)    + bf2f(pb.z >> 16))    * 0.5f;
    os[6] = (bf2f(pa.w & 0xffff) + bf2f(pb.w & 0xffff)) * 0.5f;
    os[7] = (bf2f(pa.w >> 16)    + bf2f(pb.w >> 16))    * 0.5f;
    float s = 0.f, ss = 0.f;
    #pragma unroll
    for (int i = 0; i < 8; ++i) { s += os[i]; ss += os[i] * os[i]; }
    s = wave_sum(s); ss = wave_sum(ss);
    float mu = s * (1.0f / DD);
    float var = ss * (1.0f / DD) - mu * mu;
    float rstd = rsqrtf(var + 1e-5f);
    u16 hu[8];
    #pragma unroll
    for (int i = 0; i < 8; ++i) {
        int d = lane * 8 + i;
        float h = (os[i] - mu) * rstd * sn_g[d] + sn_b[d];
        float scv = eo[(size_t)b * 1024 + d];
        float shv = eo[(size_t)b * 1024 + DD + d];
        h = h * (1.0f + scv) + shv;
        hu[i] = f2bf(silu(h));
    }
    uint4 pk;
    pk.x = (u32)hu[0] | ((u32)hu[1] << 16);
    pk.y = (u32)hu[2] | ((u32)hu[3] << 16);
    pk.z = (u32)hu[4] | ((u32)hu[5] << 16);
    pk.w = (u32)hu[6] | ((u32)hu[7] << 16);
    *(uint4*)(sbuf + (size_t)tok * DD + lane * 8) = pk;
}

// ---------------- host ----------------
extern "C" void kernel_launch(void* const* d_in, const int* in_sizes, int n_in,
                              void* d_out, int out_size, void* d_ws, size_t ws_size,
                              hipStream_t stream)
{
    const float* x      = (const float*)d_in[0];
    const float* emb    = (const float*)d_in[1];
    const float* ln_g   = (const float*)d_in[2];
    const float* ln_b   = (const float*)d_in[3];
    const float* gate_w = (const float*)d_in[4];
    const float* gate_b = (const float*)d_in[5];
    const float* w1     = (const float*)d_in[6];
    const float* b1     = (const float*)d_in[7];
    const float* w2     = (const float*)d_in[8];
    const float* b2     = (const float*)d_in[9];
    const float* emb_w  = (const float*)d_in[10];
    const float* emb_b  = (const float*)d_in[11];
    const float* sn_g   = (const float*)d_in[12];
    const float* sn_b   = (const float*)d_in[13];
    const float* out_w  = (const float*)d_in[14];
    const float* out_b  = (const float*)d_in[15];
    (void)n_in; (void)in_sizes; (void)out_size; (void)ws_size;

    const size_t szW    = (size_t)GE * FF * DD * 2;             // 33.5 MB each
    const size_t szOwt  = (size_t)DD * DD * 2;
    const size_t szH    = (size_t)NTOK * DD * 2;                // 12.85 MB
    const size_t szEo   = (size_t)BB * 2 * DD * 4;
    const size_t szP    = (size_t)NBR * NTOK * 4;
    const size_t szCnt  = 256, szMeta = 4096;
    const size_t szList = (size_t)GE * NTOK * 4;
    const size_t szU    = ((size_t)2 * NTOK + 256) * FF * 2;    // 103 MB
    const size_t szM    = (size_t)2 * NTOK * DD * 2;            // 25.7 MB (bf16)

    auto align256 = [](size_t v) { return (v + 255) & ~(size_t)255; };
    char* w = (char*)d_ws;
    size_t off = 0;
    auto take = [&](size_t bytes) -> void* {
        void* p = w + off;
        off = align256(off + bytes);
        return p;
    };
    u16*   w1t  = (u16*)take(szW);
    u16*   w2t  = (u16*)take(szW);
    u16*   owt  = (u16*)take(szOwt);
    u16*   hA   = (u16*)take(szH);       // reused as sbuf
    u16*   hB   = (u16*)take(szH);
    float* eo   = (float*)take(szEo);
    float* pbuf = (float*)take(szP);
    int*   idxb = (int*)take(szP);
    int*   cnt  = (int*)take(szCnt);
    int*   meta = (int*)take(szMeta);
    int*   list = (int*)take(szList);
    u16*   ubuf = (u16*)take(szU);
    u16*   moe  = (u16*)take(szM);

    // 1. merged front: transposes + eo + cnt init + LN/gate (one dispatch)
    front_kernel<<<NB_FRONT, 256, 0, stream>>>(w1, w1t, w2, w2t, out_w, owt,
                                               emb, emb_w, emb_b, eo, cnt,
                                               x, ln_g, ln_b, gate_w, gate_b,
                                               hA, hB, idxb, pbuf);

    // 2. routing (LDS histogram) + tile table
    route_kernel<<<NTOK / 256, 256, 0, stream>>>(idxb, cnt, list);
    tilestart_kernel<<<1, 64, 0, stream>>>(cnt, meta);

    // 3. expert FFN (flat tile queues, ntile-fastest)
    gemm_tile<0><<<dim3(FF / 128, MT128), 256, 0, stream>>>(
        hA, hB, w1t, meta, cnt, list, nullptr, b1, ubuf, nullptr);
    gemm_tile<1><<<dim3(DD / 128, MT128), 256, 0, stream>>>(
        ubuf, nullptr, w2t, meta, cnt, list, pbuf, b2, nullptr, moe);

    // 4. stylization + output projection + residual
    stylize_kernel<<<NTOK / 4, 256, 0, stream>>>(moe, eo, sn_g, sn_b, hA);
    gemm_out<<<dim3(DD / 128, NTOK / 128), 256, 0, stream>>>(
        hA, owt, out_b, x, (float*)d_out);
}

// Round 12
// 332.426 us; speedup vs baseline: 1.1955x; 1.0205x over previous
//
#include <hip/hip_runtime.h>
#include <hip/hip_bf16.h>

typedef unsigned short u16;
typedef unsigned int u32;

typedef short bf16v8 __attribute__((ext_vector_type(8)));
typedef float f32v4 __attribute__((ext_vector_type(4)));

// ---------------- problem constants ----------------
constexpr int BB   = 64;
constexpr int TT   = 196;
constexpr int NTOK = BB * TT;   // 12544
constexpr int DD   = 512;
constexpr int FF   = 2048;
constexpr int EE   = 8;
constexpr int NBR  = 2;
constexpr int GE   = NBR * EE;  // 16 global experts
constexpr int MT128 = 212;      // >= max total 128-row tiles (<=210)
// front grid: [0,512) w1 slabs; [512,768) w2 half-slabs; [768,776) out_w;
//             [776,840) eo; [840, 840+NTOK/4) ln_gate
constexpr int NB_FRONT = 840 + NTOK / 4;

// meta: [0..15] u-row base (cumsum); [33] n128; [64..64+n128) (ge<<20)|tile
__device__ __forceinline__ u16 f2bf(float f) {
    union { float f; u32 u; } v; v.f = f;
    u32 r = v.u + 0x7fffu + ((v.u >> 16) & 1u);
    return (u16)(r >> 16);
}

__device__ __forceinline__ float bf2f(u32 u) {
    union { u32 u; float f; } v; v.u = u << 16; return v.f;
}

__device__ __forceinline__ float wave_sum(float v) {
    #pragma unroll
    for (int m = 32; m > 0; m >>= 1) v += __shfl_xor(v, m, 64);
    return v;
}

// tanh-approx gelu via sigmoid: gelu(v) = v * sigmoid(1.596v + 0.0714v^3)
__device__ __forceinline__ float gelu_tanh(float v) {
    float y = 1.595769122f * v + 0.071354816f * (v * v * v);
    return v / (1.0f + __expf(-y));
}

__device__ __forceinline__ float silu(float v) {
    return v / (1.0f + __expf(-v));
}

__device__ __forceinline__ void gload16(const u16* g, u16* l) {
    typedef const __attribute__((address_space(1))) unsigned gv_t;
    typedef __attribute__((address_space(3))) unsigned lv_t;
    __builtin_amdgcn_global_load_lds((gv_t*)g, (lv_t*)l, 16, 0, 0);
}

__device__ __forceinline__ void bar() {
    asm volatile("" ::: "memory");
    __builtin_amdgcn_s_barrier();
    asm volatile("" ::: "memory");
}

#define ASM_VMCNT4 asm volatile("s_waitcnt vmcnt(4)" ::: "memory")
#define ASM_VMCNT0 asm volatile("s_waitcnt vmcnt(0)" ::: "memory")
#define ASM_LGKM0  asm volatile("s_waitcnt lgkmcnt(0)" ::: "memory")

// ---------------- merged front: slab transposes + eo + cnt init + ln_gate ---
// Slab transpose: block owns 64 dst rows ACROSS the full row length; loops
// 64x64 sub-tiles (dbuf LDS + reg prefetch) so its output rows complete as
// contiguous streams through one XCD's L2 (vs scattered 128B segments).
__global__ __launch_bounds__(256) void front_kernel(
    const float* __restrict__ w1, u16* __restrict__ w1t,
    const float* __restrict__ w2, u16* __restrict__ w2t,
    const float* __restrict__ ow, u16* __restrict__ owt,
    const float* __restrict__ emb, const float* __restrict__ emb_w,
    const float* __restrict__ emb_b, float* __restrict__ eo,
    int* __restrict__ cnt,
    const float* __restrict__ x, const float* __restrict__ ln_g,
    const float* __restrict__ ln_b, const float* __restrict__ gate_w,
    const float* __restrict__ gate_b,
    u16* __restrict__ hA, u16* __restrict__ hB,
    int* __restrict__ idxb, float* __restrict__ pbuf)
{
    __shared__ __align__(16) float smem[2 * 64 * 69];   // 35.3 KB, shared by branches
    int id = blockIdx.x;
    int t = threadIdx.x;

    if (id >= 840) {               // ---- ln_gate: 4 tokens per block ----
        int wave = t >> 6, lane = t & 63;
        int tok = (id - 840) * 4 + wave;
        const float* xr = x + (size_t)tok * DD + lane * 8;
        float4 v0 = *(const float4*)xr;
        float4 v1 = *(const float4*)(xr + 4);
        float xs[8] = {v0.x, v0.y, v0.z, v0.w, v1.x, v1.y, v1.z, v1.w};
        float s = 0.f, ss = 0.f;
        #pragma unroll
        for (int i = 0; i < 8; ++i) { s += xs[i]; ss += xs[i] * xs[i]; }
        s = wave_sum(s); ss = wave_sum(ss);
        float mu = s * (1.0f / DD);
        float var = ss * (1.0f / DD) - mu * mu;
        float rstd = rsqrtf(var + 1e-5f);

        #pragma unroll
        for (int br = 0; br < NBR; ++br) {
            u16* hb = br ? hB : hA;
            float part[8] = {0, 0, 0, 0, 0, 0, 0, 0};
            u16 hu[8];
            #pragma unroll
            for (int i = 0; i < 8; ++i) {
                int d = lane * 8 + i;
                float g = ln_g[br * DD + d], b = ln_b[br * DD + d];
                float h = (xs[i] - mu) * rstd * g + b;
                hu[i] = f2bf(h);
                const float* gw = gate_w + ((size_t)br * DD + d) * EE;
                float4 g0 = *(const float4*)gw;
                float4 g1 = *(const float4*)(gw + 4);
                part[0] += h * g0.x; part[1] += h * g0.y; part[2] += h * g0.z; part[3] += h * g0.w;
                part[4] += h * g1.x; part[5] += h * g1.y; part[6] += h * g1.z; part[7] += h * g1.w;
            }
            uint4 pk;
            pk.x = (u32)hu[0] | ((u32)hu[1] << 16);
            pk.y = (u32)hu[2] | ((u32)hu[3] << 16);
            pk.z = (u32)hu[4] | ((u32)hu[5] << 16);
            pk.w = (u32)hu[6] | ((u32)hu[7] << 16);
            *(uint4*)(hb + (size_t)tok * DD + lane * 8) = pk;

            float logit[8];
            #pragma unroll
            for (int e = 0; e < 8; ++e)
                logit[e] = wave_sum(part[e]) + gate_b[br * EE + e];
            float m = logit[0]; int bi = 0;
            #pragma unroll
            for (int e = 1; e < 8; ++e)
                if (logit[e] > m) { m = logit[e]; bi = e; }
            float sum = 0.f;
            #pragma unroll
            for (int e = 0; e < 8; ++e) sum += __expf(logit[e] - m);
            if (lane == 0) {
                idxb[br * NTOK + tok] = bi;
                pbuf[br * NTOK + tok] = 1.0f / sum;
            }
        }
        return;
    }

    if (id >= 776) {               // ---- eo: silu(emb) @ emb_w + emb_b ----
        float* se = smem;          // [4][DD]
        int id2 = id - 776;
        int cg = id2 & 3, bg = id2 >> 2;
        int b0 = bg * 4;
        int c0 = cg * 256 + t;
        for (int i = t; i < 4 * DD; i += 256) {
            int b = i >> 9, d = i & (DD - 1);
            se[b * DD + d] = silu(emb[(size_t)(b0 + b) * DD + d]);
        }
        __syncthreads();
        float acc[4] = {0, 0, 0, 0};
        for (int k = 0; k < DD; ++k) {
            float wv = emb_w[(size_t)k * 1024 + c0];
            #pragma unroll
            for (int b = 0; b < 4; ++b) acc[b] += se[b * DD + k] * wv;
        }
        float bb = emb_b[c0];
        #pragma unroll
        for (int b = 0; b < 4; ++b)
            eo[(size_t)(b0 + b) * 1024 + c0] = acc[b] + bb;
        return;
    }

    // ---- slab transpose f32[R][C] -> bf16[C][R] ----
    if (id == 0 && t < 16) cnt[t] = 0;

    const float* src; u16* dst; int C, Rfull, rowbase, c0, NIT;
    if (id < 512) {                // w1: src [512][2048], dst [2048][512]
        int e = id >> 5, cg = id & 31;
        src = w1 + (size_t)e * DD * FF; dst = w1t + (size_t)e * FF * DD;
        C = FF; Rfull = DD; rowbase = 0; c0 = cg * 64; NIT = 8;
    } else if (id < 768) {         // w2: src [2048][512], dst [512][2048], half-slabs
        int sid = id - 512; int e = sid >> 4, rem = sid & 15;
        src = w2 + (size_t)e * FF * DD; dst = w2t + (size_t)e * FF * DD;
        C = DD; Rfull = FF; rowbase = (rem >> 3) * 1024; c0 = (rem & 7) * 64; NIT = 16;
    } else {                       // out_w: [512][512]
        int cg = id - 768;
        src = ow; dst = owt;
        C = DD; Rfull = DD; rowbase = 0; c0 = cg * 64; NIT = 8;
    }

    float (*tile)[64][69] = (float (*)[64][69])smem;
    int tx = t & 15, ty = t >> 4;
    int wc = t & 7, wr0 = t >> 3;

    {   // prologue: sub-tile 0 -> buf 0
        float4 v[4];
        #pragma unroll
        for (int j = 0; j < 4; ++j)
            v[j] = *(const float4*)&src[(size_t)(rowbase + ty + 16 * j) * C + c0 + tx * 4];
        #pragma unroll
        for (int j = 0; j < 4; ++j) {
            int row = ty + 16 * j;
            tile[0][row][tx * 4 + 0] = v[j].x;
            tile[0][row][tx * 4 + 1] = v[j].y;
            tile[0][row][tx * 4 + 2] = v[j].z;
            tile[0][row][tx * 4 + 3] = v[j].w;
        }
        __syncthreads();
    }

    for (int it = 0; it < NIT; ++it) {
        int cur = it & 1;
        bool pre = (it + 1 < NIT);
        float4 nv[4];
        if (pre) {                 // issue next sub-tile's loads early
            #pragma unroll
            for (int j = 0; j < 4; ++j)
                nv[j] = *(const float4*)&src[(size_t)(rowbase + (it + 1) * 64 + ty + 16 * j) * C + c0 + tx * 4];
        }
        // pack + store from tile[cur] (covers the loads above)
        #pragma unroll
        for (int p = 0; p < 2; ++p) {
            int cc = wr0 + p * 32;
            u16 pk[8];
            #pragma unroll
            for (int i = 0; i < 8; ++i)
                pk[i] = f2bf(tile[cur][wc * 8 + i][cc]);
            uint4 vv;
            vv.x = (u32)pk[0] | ((u32)pk[1] << 16);
            vv.y = (u32)pk[2] | ((u32)pk[3] << 16);
            vv.z = (u32)pk[4] | ((u32)pk[5] << 16);
            vv.w = (u32)pk[6] | ((u32)pk[7] << 16);
            *(uint4*)&dst[(size_t)(c0 + cc) * Rfull + rowbase + it * 64 + wc * 8] = vv;
        }
        if (pre) {
            #pragma unroll
            for (int j = 0; j < 4; ++j) {
                int row = ty + 16 * j;
                tile[cur ^ 1][row][tx * 4 + 0] = nv[j].x;
                tile[cur ^ 1][row][tx * 4 + 1] = nv[j].y;
                tile[cur ^ 1][row][tx * 4 + 2] = nv[j].z;
                tile[cur ^ 1][row][tx * 4 + 3] = nv[j].w;
            }
        }
        __syncthreads();
    }
}

// ---------------- routing: LDS histogram, 16 global atomics per block -------
__global__ __launch_bounds__(256) void route_kernel(
    const int* __restrict__ idxb, int* __restrict__ cnt, int* __restrict__ list)
{
    __shared__ int lcnt[GE];
    __shared__ int gbase[GE];
    int tid = threadIdx.x;
    int t = blockIdx.x * 256 + tid;
    if (tid < GE) lcnt[tid] = 0;
    __syncthreads();
    int e0 = idxb[t];
    int e1 = EE + idxb[NTOK + t];
    int r0 = atomicAdd(&lcnt[e0], 1);
    int r1 = atomicAdd(&lcnt[e1], 1);
    __syncthreads();
    if (tid < GE) {
        int c = lcnt[tid];
        gbase[tid] = c ? atomicAdd(&cnt[tid], c) : 0;
    }
    __syncthreads();
    list[(size_t)e0 * NTOK + gbase[e0] + r0] = t;
    list[(size_t)e1 * NTOK + gbase[e1] + r1] = t;
}

// ---------------- tile table (128-row granular) -----------------------------
__global__ void tilestart_kernel(const int* __restrict__ cnt, int* __restrict__ meta)
{
    int lane = threadIdx.x;   // 64 threads
    if (lane < 16) {
        int pbv = 0;
        for (int k = 0; k < lane; ++k) pbv += cnt[k];
        meta[lane] = pbv;
    }
    if (lane == 16) {
        int n = 0;
        for (int k = 0; k < 16; ++k) n += (cnt[k] + 127) >> 7;
        meta[33] = n;
    }
    for (int j = lane; j < MT128; j += 64) {
        int ge = -1, start = 0, tt = 0;
        #pragma unroll
        for (int k = 0; k < 16; ++k) {
            int mt = (cnt[k] + 127) >> 7;
            if (ge < 0) {
                if (j < start + mt) { ge = k; tt = j - start; }
                else start += mt;
            }
        }
        if (ge >= 0) meta[64 + j] = (ge << 20) | tt;
    }
}

// ---------------- 128x128 MFMA GEMM, BK=32, dbuf, counted vmcnt, 4 blk/CU ---
// MODE 0: u[pos] = gelu(h[tok] @ W1[ge] + b1[ge])      A gathered via list
// MODE 1: moe{plane}[tok] = p * (u[pos] @ W2[ge] + b2) A dense, bf16 out
// grid: (ntile, tileidx) — ntile fastest for A-tile L2 reuse
template<int MODE>
__global__ __launch_bounds__(256, 4) void gemm_tile(
    const u16* __restrict__ A0, const u16* __restrict__ A1,
    const u16* __restrict__ Bt,
    const int* __restrict__ meta, const int* __restrict__ cnt,
    const int* __restrict__ list, const float* __restrict__ pbuf,
    const float* __restrict__ bias,
    u16* __restrict__ uout, u16* __restrict__ moeout)
{
    constexpr int K = (MODE == 1) ? FF : DD;
    constexpr int N = (MODE == 0) ? FF : DD;
    constexpr int NSTEP = K / 32;

    __shared__ __align__(16) u16 As[2][128 * 32];
    __shared__ __align__(16) u16 Bs[2][128 * 32];
    __shared__ int rowtok[128];
    __shared__ float rowp[128];

    int ntile = blockIdx.x;
    int j = blockIdx.y;
    if (j >= meta[33]) return;
    int ev = meta[64 + j];
    int ge = ev >> 20;
    int rb = (ev & 0xfffff) << 7;
    int cnt_e = cnt[ge];
    int pb = meta[ge];

    int tid = threadIdx.x, wave = tid >> 6, lane = tid & 63;
    int wm = wave >> 1, wn = wave & 1;
    int fr = lane & 15, fq = lane >> 4;
    int r0 = wave * 16 + (lane >> 2);
    int sc = (lane & 3) ^ ((lane >> 3) & 3);   // swizzled source chunk (bank fix)

    const u16* Abase;
    if constexpr (MODE == 0) Abase = (ge >= 8) ? A1 : A0;
    else                     Abase = A0;
    const u16* Bte = Bt + (size_t)ge * FF * DD;

    const u16 *aSrc0, *aSrc1, *bSrc0, *bSrc1;
    if constexpr (MODE == 0) {
        int lb = ge * NTOK;
        int g0 = rb + r0, g1 = g0 + 64;
        int t0 = (g0 < cnt_e) ? list[lb + g0] : list[lb];
        int t1 = (g1 < cnt_e) ? list[lb + g1] : list[lb];
        aSrc0 = Abase + (size_t)t0 * K + sc * 8;
        aSrc1 = Abase + (size_t)t1 * K + sc * 8;
    } else {
        size_t base = (size_t)(pb + rb);
        aSrc0 = Abase + (base + r0) * (size_t)K + sc * 8;
        aSrc1 = Abase + (base + r0 + 64) * (size_t)K + sc * 8;
    }
    {
        int nrow = ntile * 128 + r0;
        bSrc0 = Bte + (size_t)nrow * K + sc * 8;
        bSrc1 = Bte + (size_t)(nrow + 64) * K + sc * 8;
    }

    if constexpr (MODE == 1) {
        if (tid < 128) {
            int g = rb + tid;
            int tk = (g < cnt_e) ? list[ge * NTOK + g] : -1;
            rowtok[tid] = tk;
            rowp[tid] = (tk >= 0) ? pbuf[(ge >> 3) * NTOK + tk] : 0.f;
        }
        ASM_LGKM0;
    }

    f32v4 acc[4][4];
    #pragma unroll
    for (int mi = 0; mi < 4; ++mi)
        #pragma unroll
        for (int ni = 0; ni < 4; ++ni)
            acc[mi][ni] = (f32v4){0.f, 0.f, 0.f, 0.f};

    int ch = fq ^ ((fr >> 1) & 3);             // swizzled read chunk (bank fix)

    // ---- prologue: stage step 0 into buf 0 ----
    gload16(aSrc0, &As[0][wave * 512]);
    gload16(aSrc1, &As[0][2048 + wave * 512]);
    gload16(bSrc0, &Bs[0][wave * 512]);
    gload16(bSrc1, &Bs[0][2048 + wave * 512]);
    aSrc0 += 32; aSrc1 += 32; bSrc0 += 32; bSrc1 += 32;

    #pragma unroll 2
    for (int t = 0; t < NSTEP; ++t) {
        const int cur = t & 1;
        if (t + 1 < NSTEP) {
            gload16(aSrc0, &As[cur ^ 1][wave * 512]);
            gload16(aSrc1, &As[cur ^ 1][2048 + wave * 512]);
            gload16(bSrc0, &Bs[cur ^ 1][wave * 512]);
            gload16(bSrc1, &Bs[cur ^ 1][2048 + wave * 512]);
            aSrc0 += 32; aSrc1 += 32; bSrc0 += 32; bSrc1 += 32;
            ASM_VMCNT4;    // step t's 4 loads landed; step t+1's 4 in flight
        } else {
            ASM_VMCNT0;
        }
        bar();

        bf16v8 af[4], bfr[4];
        #pragma unroll
        for (int mi = 0; mi < 4; ++mi)
            af[mi] = *(const bf16v8*)&As[cur][(wm * 64 + mi * 16 + fr) * 32 + ch * 8];
        #pragma unroll
        for (int ni = 0; ni < 4; ++ni)
            bfr[ni] = *(const bf16v8*)&Bs[cur][(wn * 64 + ni * 16 + fr) * 32 + ch * 8];
        #pragma unroll
        for (int mi = 0; mi < 4; ++mi)
            #pragma unroll
            for (int ni = 0; ni < 4; ++ni)
                acc[mi][ni] = __builtin_amdgcn_mfma_f32_16x16x32_bf16(
                    af[mi], bfr[ni], acc[mi][ni], 0, 0, 0);
        bar();
    }

    // ---- epilogue (C/D frag: col = lane&15, row = fq*4 + reg) ----
    #pragma unroll
    for (int mi = 0; mi < 4; ++mi) {
        #pragma unroll
        for (int ni = 0; ni < 4; ++ni) {
            int col = ntile * 128 + wn * 64 + ni * 16 + fr;
            float bn = bias[(size_t)ge * N + col];
            #pragma unroll
            for (int r = 0; r < 4; ++r) {
                int rr = wm * 64 + mi * 16 + fq * 4 + r;
                float v = acc[mi][ni][r] + bn;
                if constexpr (MODE == 0) {
                    if (rb + rr < cnt_e)
                        uout[(size_t)(pb + rb + rr) * FF + col] = f2bf(gelu_tanh(v));
                } else {
                    int tok = rowtok[rr];
                    if (tok >= 0)
                        moeout[((size_t)(ge >> 3) * NTOK + tok) * DD + col] =
                            f2bf(v * rowp[rr]);
                }
            }
        }
    }
}

// ---------------- 128x128 GEMM (output projection only) ---------------------
// dout = xres + A @ owt + out_b  (A dense bf16, f32 out)
__global__ __launch_bounds__(256, 4) void gemm_out(
    const u16* __restrict__ A0, const u16* __restrict__ Bt,
    const float* __restrict__ bias,
    const float* __restrict__ xres, float* __restrict__ dout)
{
    constexpr int K = DD;
    constexpr int NSTEP = K / 32;

    __shared__ __align__(16) u16 As[2][128 * 32];
    __shared__ __align__(16) u16 Bs[2][128 * 32];

    int ntile = blockIdx.x;
    int rb = blockIdx.y * 128;

    int tid = threadIdx.x, wave = tid >> 6, lane = tid & 63;
    int wm = wave >> 1, wn = wave & 1;
    int fr = lane & 15, fq = lane >> 4;
    int r0 = wave * 16 + (lane >> 2);
    int sc = (lane & 3) ^ ((lane >> 3) & 3);

    const u16 *aSrc0, *aSrc1, *bSrc0, *bSrc1;
    aSrc0 = A0 + (size_t)(rb + r0) * K + sc * 8;
    aSrc1 = A0 + (size_t)(rb + r0 + 64) * K + sc * 8;
    {
        int nrow = ntile * 128 + r0;
        bSrc0 = Bt + (size_t)nrow * K + sc * 8;
        bSrc1 = Bt + (size_t)(nrow + 64) * K + sc * 8;
    }

    f32v4 acc[4][4];
    #pragma unroll
    for (int mi = 0; mi < 4; ++mi)
        #pragma unroll
        for (int ni = 0; ni < 4; ++ni)
            acc[mi][ni] = (f32v4){0.f, 0.f, 0.f, 0.f};

    int ch = fq ^ ((fr >> 1) & 3);

    gload16(aSrc0, &As[0][wave * 512]);
    gload16(aSrc1, &As[0][2048 + wave * 512]);
    gload16(bSrc0, &Bs[0][wave * 512]);
    gload16(bSrc1, &Bs[0][2048 + wave * 512]);
    aSrc0 += 32; aSrc1 += 32; bSrc0 += 32; bSrc1 += 32;

    #pragma unroll 2
    for (int t = 0; t < NSTEP; ++t) {
        const int cur = t & 1;
        if (t + 1 < NSTEP) {
            gload16(aSrc0, &As[cur ^ 1][wave * 512]);
            gload16(aSrc1, &As[cur ^ 1][2048 + wave * 512]);
            gload16(bSrc0, &Bs[cur ^ 1][wave * 512]);
            gload16(bSrc1, &Bs[cur ^ 1][2048 + wave * 512]);
            aSrc0 += 32; aSrc1 += 32; bSrc0 += 32; bSrc1 += 32;
            ASM_VMCNT4;
        } else {
            ASM_VMCNT0;
        }
        bar();

        bf16v8 af[4], bfr[4];
        #pragma unroll
        for (int mi = 0; mi < 4; ++mi)
            af[mi] = *(const bf16v8*)&As[cur][(wm * 64 + mi * 16 + fr) * 32 + ch * 8];
        #pragma unroll
        for (int ni = 0; ni < 4; ++ni)
            bfr[ni] = *(const bf16v8*)&Bs[cur][(wn * 64 + ni * 16 + fr) * 32 + ch * 8];
        #pragma unroll
        for (int mi = 0; mi < 4; ++mi)
            #pragma unroll
            for (int ni = 0; ni < 4; ++ni)
                acc[mi][ni] = __builtin_amdgcn_mfma_f32_16x16x32_bf16(
                    af[mi], bfr[ni], acc[mi][ni], 0, 0, 0);
        bar();
    }

    #pragma unroll
    for (int mi = 0; mi < 4; ++mi) {
        #pragma unroll
        for (int ni = 0; ni < 4; ++ni) {
            int col = ntile * 128 + wn * 64 + ni * 16 + fr;
            float bn = bias[col];
            #pragma unroll
            for (int r = 0; r < 4; ++r) {
                int rr = wm * 64 + mi * 16 + fq * 4 + r;
                size_t o = (size_t)(rb + rr) * DD + col;
                dout[o] = xres[o] + acc[mi][ni][r] + bn;
            }
        }
    }
}

// ---------------- stylize: LN((moe0+moe1)/2)*(1+scale)+shift -> silu -> bf16
__global__ __launch_bounds__(256) void stylize_kernel(
    const u16* __restrict__ moe, const float* __restrict__ eo,
    const float* __restrict__ sn_g, const float* __restrict__ sn_b,
    u16* __restrict__ sbuf)
{
    int wave = threadIdx.x >> 6, lane = threadIdx.x & 63;
    int tok = blockIdx.x * 4 + wave;
    int b = tok / TT;
    const u16* mr = moe + (size_t)tok * DD + lane * 8;
    const u16* mr2 = mr + (size_t)NTOK * DD;
    uint4 pa = *(const uint4*)mr;
    uint4 pb = *(const uint4*)mr2;
    float os[8];
    os[0] = (bf2f(pa.x & 0xffff) + bf2f(pb.x & 0xffff)) * 0.5f;
    os[1] = (bf2f(pa.x >> 16)    + bf2f(pb.x >> 16))    * 0.5f;
    os[2] = (bf2f(pa.y & 0xffff) + bf2f(pb.y & 0xffff)) * 0.5f;
    os[3] = (bf2f(pa.y >> 16)    + bf2f(pb.y >> 16))    * 0.5f;
    os[4] = (bf2f(pa.z & 0xffff) + bf2f(pb.z & 0xffff)) * 0.5f;
    os[5] = (bf2f(pa.z >> 16)    + bf2f(pb.z >> 16))    * 0.5f;
    os[6] = (bf2f(pa.w & 0xffff) + bf2f(pb.w & 0xffff)) * 0.5f;
    os[7] = (bf2f(pa.w >> 16)    + bf2f(pb.w >> 16))    * 0.5f;
    float s = 0.f, ss = 0.f;
    #pragma unroll
    for (int i = 0; i < 8; ++i) { s += os[i]; ss += os[i] * os[i]; }
    s = wave_sum(s); ss = wave_sum(ss);
    float mu = s * (1.0f / DD);
    float var = ss * (1.0f / DD) - mu * mu;
    float rstd = rsqrtf(var + 1e-5f);
    u16 hu[8];
    #pragma unroll
    for (int i = 0; i < 8; ++i) {
        int d = lane * 8 + i;
        float h = (os[i] - mu) * rstd * sn_g[d] + sn_b[d];
        float scv = eo[(size_t)b * 1024 + d];
        float shv = eo[(size_t)b * 1024 + DD + d];
        h = h * (1.0f + scv) + shv;
        hu[i] = f2bf(silu(h));
    }
    uint4 pk;
    pk.x = (u32)hu[0] | ((u32)hu[1] << 16);
    pk.y = (u32)hu[2] | ((u32)hu[3] << 16);
    pk.z = (u32)hu[4] | ((u32)hu[5] << 16);
    pk.w = (u32)hu[6] | ((u32)hu[7] << 16);
    *(uint4*)(sbuf + (size_t)tok * DD + lane * 8) = pk;
}

// ---------------- host ----------------
extern "C" void kernel_launch(void* const* d_in, const int* in_sizes, int n_in,
                              void* d_out, int out_size, void* d_ws, size_t ws_size,
                              hipStream_t stream)
{
    const float* x      = (const float*)d_in[0];
    const float* emb    = (const float*)d_in[1];
    const float* ln_g   = (const float*)d_in[2];
    const float* ln_b   = (const float*)d_in[3];
    const float* gate_w = (const float*)d_in[4];
    const float* gate_b = (const float*)d_in[5];
    const float* w1     = (const float*)d_in[6];
    const float* b1     = (const float*)d_in[7];
    const float* w2     = (const float*)d_in[8];
    const float* b2     = (const float*)d_in[9];
    const float* emb_w  = (const float*)d_in[10];
    const float* emb_b  = (const float*)d_in[11];
    const float* sn_g   = (const float*)d_in[12];
    const float* sn_b   = (const float*)d_in[13];
    const float* out_w  = (const float*)d_in[14];
    const float* out_b  = (const float*)d_in[15];
    (void)n_in; (void)in_sizes; (void)out_size; (void)ws_size;

    const size_t szW    = (size_t)GE * FF * DD * 2;             // 33.5 MB each
    const size_t szOwt  = (size_t)DD * DD * 2;
    const size_t szH    = (size_t)NTOK * DD * 2;                // 12.85 MB
    const size_t szEo   = (size_t)BB * 2 * DD * 4;
    const size_t szP    = (size_t)NBR * NTOK * 4;
    const size_t szCnt  = 256, szMeta = 4096;
    const size_t szList = (size_t)GE * NTOK * 4;
    const size_t szU    = ((size_t)2 * NTOK + 256) * FF * 2;    // 103 MB
    const size_t szM    = (size_t)2 * NTOK * DD * 2;            // 25.7 MB (bf16)

    auto align256 = [](size_t v) { return (v + 255) & ~(size_t)255; };
    char* w = (char*)d_ws;
    size_t off = 0;
    auto take = [&](size_t bytes) -> void* {
        void* p = w + off;
        off = align256(off + bytes);
        return p;
    };
    u16*   w1t  = (u16*)take(szW);
    u16*   w2t  = (u16*)take(szW);
    u16*   owt  = (u16*)take(szOwt);
    u16*   hA   = (u16*)take(szH);       // reused as sbuf
    u16*   hB   = (u16*)take(szH);
    float* eo   = (float*)take(szEo);
    float* pbuf = (float*)take(szP);
    int*   idxb = (int*)take(szP);
    int*   cnt  = (int*)take(szCnt);
    int*   meta = (int*)take(szMeta);
    int*   list = (int*)take(szList);
    u16*   ubuf = (u16*)take(szU);
    u16*   moe  = (u16*)take(szM);

    // 1. merged front: slab transposes + eo + cnt init + LN/gate (one dispatch)
    front_kernel<<<NB_FRONT, 256, 0, stream>>>(w1, w1t, w2, w2t, out_w, owt,
                                               emb, emb_w, emb_b, eo, cnt,
                                               x, ln_g, ln_b, gate_w, gate_b,
                                               hA, hB, idxb, pbuf);

    // 2. routing (LDS histogram) + tile table
    route_kernel<<<NTOK / 256, 256, 0, stream>>>(idxb, cnt, list);
    tilestart_kernel<<<1, 64, 0, stream>>>(cnt, meta);

    // 3. expert FFN (flat tile queues, ntile-fastest)
    gemm_tile<0><<<dim3(FF / 128, MT128), 256, 0, stream>>>(
        hA, hB, w1t, meta, cnt, list, nullptr, b1, ubuf, nullptr);
    gemm_tile<1><<<dim3(DD / 128, MT128), 256, 0, stream>>>(
        ubuf, nullptr, w2t, meta, cnt, list, pbuf, b2, nullptr, moe);

    // 4. stylization + output projection + residual
    stylize_kernel<<<NTOK / 4, 256, 0, stream>>>(moe, eo, sn_g, sn_b, hA);
    gemm_out<<<dim3(DD / 128, NTOK / 128), 256, 0, stream>>>(
        hA, owt, out_b, x, (float*)d_out);
}